// Round 1
// baseline (258.745 us; speedup 1.0000x reference)
//
#include <hip/hip_runtime.h>

#define LPC_N 32
#define LPC_EPS 1e-5f

__global__ __launch_bounds__(256) void levinson_kernel(
    const float* __restrict__ pAC,   // [N+1, T]
    float* __restrict__ out,         // [N, T]
    int T)
{
    int t = blockIdx.x * blockDim.x + threadIdx.x;
    if (t >= T) return;

    // Load autocorrelation column into registers (33 coalesced loads).
    float ac[LPC_N + 1];
#pragma unroll
    for (int i = 0; i <= LPC_N; ++i) {
        ac[i] = pAC[i * T + t];
    }

    float lp[LPC_N];
    float E = ac[0];

#pragma unroll
    for (int i = 0; i < LPC_N; ++i) {
        // acc = ac[i+1] + sum_{j<i} lp[j] * ac[i-j]
        float acc = ac[i + 1];
#pragma unroll
        for (int j = 0; j < i; ++j) {
            acc += lp[j] * ac[i - j];
        }
        float ki = acc / E;
        float c = 1.0f - ki * ki;
        c = (c < LPC_EPS) ? LPC_EPS : c;
        E *= c;

        // lp[j] = lp[j] - ki * lp[i-1-j] using OLD values: pairwise update.
#pragma unroll
        for (int j = 0; j < i - 1 - j; ++j) {
            float a = lp[j];
            float b = lp[i - 1 - j];
            lp[j]         = a - ki * b;
            lp[i - 1 - j] = b - ki * a;
        }
        if (i & 1) {
            int m = (i - 1) >> 1;   // self-paired middle element
            lp[m] = lp[m] - ki * lp[m];
        }
        lp[i] = -ki;
    }

    // Store (32 coalesced stores).
#pragma unroll
    for (int i = 0; i < LPC_N; ++i) {
        out[i * T + t] = lp[i];
    }
}

extern "C" void kernel_launch(void* const* d_in, const int* in_sizes, int n_in,
                              void* d_out, int out_size, void* d_ws, size_t ws_size,
                              hipStream_t stream)
{
    const float* pAC = (const float*)d_in[0];
    float* out = (float*)d_out;
    int T = in_sizes[0] / (LPC_N + 1);   // 1048576

    int block = 256;
    int grid = (T + block - 1) / block;
    levinson_kernel<<<grid, block, 0, stream>>>(pAC, out, T);
}

// Round 2
// 242.577 us; speedup vs baseline: 1.0667x; 1.0667x over previous
//
#include <hip/hip_runtime.h>

#define LPC_N 32
#define LPC_EPS 1e-5f

typedef float f2 __attribute__((ext_vector_type(2)));

__device__ __forceinline__ f2 rcp2(f2 v) {
    f2 r;
    r.x = __builtin_amdgcn_rcpf(v.x);
    r.y = __builtin_amdgcn_rcpf(v.y);
    return r;
}

// One thread processes TWO adjacent frames (float2 lanes -> v_pk_fma_f32).
__global__ __launch_bounds__(256) void levinson_kernel(
    const float* __restrict__ pAC,   // [N+1, T]
    float* __restrict__ out,         // [N, T]
    int T)
{
    int p = blockIdx.x * blockDim.x + threadIdx.x;  // frame-pair index
    int TP = T >> 1;
    if (p >= TP) return;

    // 33 coalesced dwordx2 loads (8 B/lane).
    f2 ac[LPC_N + 1];
#pragma unroll
    for (int i = 0; i <= LPC_N; ++i) {
        ac[i] = *(const f2*)(pAC + (size_t)i * T + 2 * (size_t)p);
    }

    f2 lp[LPC_N];
    f2 E = ac[0];

#pragma unroll
    for (int i = 0; i < LPC_N; ++i) {
        // rcp(E) issued first: its latency hides under the dot product below.
        f2 invE = rcp2(E);

        // acc = ac[i+1] + sum_{j<i} lp[j]*ac[i-j], two independent FMA chains.
        f2 s0 = ac[i + 1];
        f2 s1 = {0.0f, 0.0f};
#pragma unroll
        for (int j = 0; j + 1 < i; j += 2) {
            s0 += lp[j]     * ac[i - j];
            s1 += lp[j + 1] * ac[i - j - 1];
        }
        if (i & 1) {                       // leftover j = i-1 when i is odd
            s0 += lp[i - 1] * ac[1];
        }
        f2 acc = s0 + s1;

        f2 ki = acc * invE;
        f2 c  = {1.0f, 1.0f};
        c -= ki * ki;
        c.x = fmaxf(c.x, LPC_EPS);
        c.y = fmaxf(c.y, LPC_EPS);
        E *= c;

        // lp[j] = lp[j] - ki*lp[i-1-j] from OLD lp: pairwise swap update.
#pragma unroll
        for (int j = 0; j < i - 1 - j; ++j) {
            f2 a = lp[j];
            f2 b = lp[i - 1 - j];
            lp[j]         = a - ki * b;
            lp[i - 1 - j] = b - ki * a;
        }
        if (i & 1) {
            int m = (i - 1) >> 1;          // self-paired middle element
            lp[m] = lp[m] - ki * lp[m];
        }
        lp[i] = -ki;
    }

    // 32 coalesced dwordx2 stores.
#pragma unroll
    for (int i = 0; i < LPC_N; ++i) {
        *(f2*)(out + (size_t)i * T + 2 * (size_t)p) = lp[i];
    }
}

extern "C" void kernel_launch(void* const* d_in, const int* in_sizes, int n_in,
                              void* d_out, int out_size, void* d_ws, size_t ws_size,
                              hipStream_t stream)
{
    const float* pAC = (const float*)d_in[0];
    float* out = (float*)d_out;
    int T = in_sizes[0] / (LPC_N + 1);   // 1048576

    int TP = T >> 1;                     // frame pairs
    int block = 256;
    int grid = (TP + block - 1) / block;
    levinson_kernel<<<grid, block, 0, stream>>>(pAC, out, T);
}